// Round 7
// baseline (357.780 us; speedup 1.0000x reference)
//
#include <hip/hip_runtime.h>
#include <hip/hip_bf16.h>
#include <stdint.h>

#define NN 50000
#define NE 600000
#define NP 200000
#define SCAN_CHUNK 1024
#define NB_SCAN ((NN + SCAN_CHUNK - 1) / SCAN_CHUNK)   // 49

typedef __attribute__((ext_vector_type(8))) short short8;
typedef __attribute__((ext_vector_type(4))) float f32x4;

static __device__ __forceinline__ unsigned short f2bf(float f) {
  union { float f; unsigned u; } a; a.f = f;
  unsigned r = a.u + 0x7fff + ((a.u >> 16) & 1);
  return (unsigned short)(r >> 16);
}
static __device__ __forceinline__ float bf2f(unsigned short h) {
  union { unsigned u; float f; } a; a.u = ((unsigned)h) << 16;
  return a.f;
}
static __device__ __forceinline__ float lo16f(unsigned w) {
  union { unsigned u; float f; } a; a.u = w << 16; return a.f;
}
static __device__ __forceinline__ float hi16f(unsigned w) {
  union { unsigned u; float f; } a; a.u = w & 0xffff0000u; return a.f;
}

// ---------------- graph build ----------------

__global__ void count_kernel(const int* __restrict__ rows, int* __restrict__ counts) {
  int e = blockIdx.x * 256 + threadIdx.x;
  if (e < NE) atomicAdd(&counts[rows[e]], 1);
}

__global__ void dis_kernel(const int* __restrict__ counts, float* __restrict__ dis) {
  int i = blockIdx.x * 256 + threadIdx.x;
  if (i < NN) dis[i] = rsqrtf((float)counts[i] + 1.0f);
}

__global__ __launch_bounds__(256) void scan_partial(const int* __restrict__ counts,
                                                    int* __restrict__ bsum) {
  const int b = blockIdx.x, t = threadIdx.x;
  const int base = b * SCAN_CHUNK;
  int s = 0;
  for (int j = t; j < SCAN_CHUNK; j += 256) {
    int i = base + j;
    if (i < NN) s += counts[i];
  }
  __shared__ int red[4];
#pragma unroll
  for (int off = 32; off; off >>= 1) s += __shfl_down(s, off);
  if ((t & 63) == 0) red[t >> 6] = s;
  __syncthreads();
  if (t == 0) bsum[b] = red[0] + red[1] + red[2] + red[3];
}

__global__ void scan_mid(const int* __restrict__ bsum, int* __restrict__ bbase) {
  int t = threadIdx.x;  // 64 threads, one wave
  int v = (t < NB_SCAN) ? bsum[t] : 0;
  int orig = v;
#pragma unroll
  for (int off = 1; off < 64; off <<= 1) {
    int u = __shfl_up(v, off);
    if (t >= off) v += u;
  }
  if (t < NB_SCAN) bbase[t] = v - orig;
}

__global__ __launch_bounds__(256) void scan_final(const int* __restrict__ counts,
                                                  const int* __restrict__ bbase,
                                                  int* __restrict__ row_ptr,
                                                  int* __restrict__ cursor) {
  const int b = blockIdx.x, t = threadIdx.x;
  const int i0 = b * SCAN_CHUNK + t * 4;
  int c[4]; int s = 0;
#pragma unroll
  for (int r = 0; r < 4; ++r) { int i = i0 + r; c[r] = (i < NN) ? counts[i] : 0; s += c[r]; }
  __shared__ int sc[256];
  sc[t] = s;
  __syncthreads();
  for (int off = 1; off < 256; off <<= 1) {
    int add = (t >= off) ? sc[t - off] : 0;
    __syncthreads();
    sc[t] += add;
    __syncthreads();
  }
  int run = bbase[b] + sc[t] - s;
#pragma unroll
  for (int r = 0; r < 4; ++r) {
    int i = i0 + r;
    if (i < NN) { row_ptr[i] = run; cursor[i] = run; run += c[r]; }
  }
  if (b == 0 && t == 0) row_ptr[NN] = NE;
}

__global__ void fill_kernel(const int* __restrict__ rows, const int* __restrict__ cols,
                            int* __restrict__ cursor, int* __restrict__ csr_col) {
  int e = blockIdx.x * 256 + threadIdx.x;
  if (e < NE) {
    int r = rows[e];
    int pos = atomicAdd(&cursor[r], 1);
    csr_col[pos] = cols[e];
  }
}

// ---------------- weight prep ----------------

__global__ void prep_w(const float* __restrict__ embW, const float* __restrict__ convW,
                       const float* __restrict__ W1, const float* __restrict__ W2,
                       unsigned short* __restrict__ embT_hi, unsigned short* __restrict__ embT_lo,
                       unsigned short* __restrict__ convT_hi, unsigned short* __restrict__ convT_lo,
                       unsigned short* __restrict__ W1T, unsigned short* __restrict__ W2T) {
  int idx = blockIdx.x * 256 + threadIdx.x;
  if (idx < 8192) {
    int n = idx >> 6, k = idx & 63;
    float v = embW[(size_t)k * 128 + n];
    unsigned short h = f2bf(v);
    embT_hi[idx] = h;
    embT_lo[idx] = f2bf(v - bf2f(h));
  } else if (idx < 8192 + 49152) {
    int i2 = idx - 8192;
    int l = i2 >> 14, n = (i2 >> 7) & 127, k = i2 & 127;
    float v = convW[(size_t)l * 16384 + (size_t)k * 128 + n];
    unsigned short h = f2bf(v);
    convT_hi[i2] = h;
    convT_lo[i2] = f2bf(v - bf2f(h));
  } else if (idx < 8192 + 49152 + 36864) {
    int i3 = idx - 57344;
    int n = i3 / 288, k = i3 % 288;
    W1T[i3] = f2bf(W1[(size_t)k * 128 + n]);
  } else if (idx < 8192 + 49152 + 36864 + 8192) {
    int i4 = idx - 94208;
    int n = i4 >> 7, k = i4 & 127;
    W2T[i4] = f2bf(W2[(size_t)k * 64 + n]);
  }
}

// ---------------- split-bf16 MFMA GEMM (embed only) ----------------
// A fp32 split in-register; B prepacked hi/lo. v = dis[row]*(acc + bias) -> bf16

__global__ __launch_bounds__(256) void embed_gemm(
    const float* __restrict__ Af,
    const unsigned short* __restrict__ BThi, const unsigned short* __restrict__ BTlo,
    const float* __restrict__ bias, const float* __restrict__ dis,
    unsigned short* __restrict__ outb, int M) {
  const int K = 64;
  const int tid  = threadIdx.x;
  const int lane = tid & 63;
  const int w    = tid >> 6;
  const int l15  = lane & 15;
  const int khi  = (lane >> 4) * 8;
  const int rowb = blockIdx.x * 128 + w * 32;

  int ar[2];
#pragma unroll
  for (int rt = 0; rt < 2; ++rt) {
    int r = rowb + rt * 16 + l15;
    ar[rt] = (r < M) ? r : M - 1;
  }

  f32x4 acc[2][8];
#pragma unroll
  for (int rt = 0; rt < 2; ++rt)
#pragma unroll
    for (int ct = 0; ct < 8; ++ct) acc[rt][ct] = (f32x4){0.f, 0.f, 0.f, 0.f};

#pragma unroll
  for (int kb = 0; kb < K; kb += 32) {
    short8 ahi[2], alo[2];
#pragma unroll
    for (int rt = 0; rt < 2; ++rt) {
      const float* asrc = Af + (size_t)ar[rt] * K + kb + khi;
      float4 va0 = *(const float4*)(asrc);
      float4 va1 = *(const float4*)(asrc + 4);
      float av[8] = {va0.x, va0.y, va0.z, va0.w, va1.x, va1.y, va1.z, va1.w};
#pragma unroll
      for (int j = 0; j < 8; ++j) {
        unsigned short h = f2bf(av[j]);
        ahi[rt][j] = (short)h;
        alo[rt][j] = (short)f2bf(av[j] - bf2f(h));
      }
    }
#pragma unroll
    for (int ct = 0; ct < 8; ++ct) {
      size_t woff = (size_t)(ct * 16 + l15) * K + kb + khi;
      short8 bhi = *(const short8*)(BThi + woff);
      short8 blo = *(const short8*)(BTlo + woff);
#pragma unroll
      for (int rt = 0; rt < 2; ++rt) {
        acc[rt][ct] = __builtin_amdgcn_mfma_f32_16x16x32_bf16(ahi[rt], bhi, acc[rt][ct], 0, 0, 0);
        acc[rt][ct] = __builtin_amdgcn_mfma_f32_16x16x32_bf16(alo[rt], bhi, acc[rt][ct], 0, 0, 0);
        acc[rt][ct] = __builtin_amdgcn_mfma_f32_16x16x32_bf16(ahi[rt], blo, acc[rt][ct], 0, 0, 0);
      }
    }
  }

#pragma unroll
  for (int rt = 0; rt < 2; ++rt) {
    const int orow0 = rowb + rt * 16 + (lane >> 4) * 4;
    float dv[4];
#pragma unroll
    for (int r = 0; r < 4; ++r) dv[r] = (orow0 + r < M) ? dis[orow0 + r] : 0.f;
#pragma unroll
    for (int ct = 0; ct < 8; ++ct) {
      int col = ct * 16 + l15;
      float bb = bias[col];
#pragma unroll
      for (int r = 0; r < 4; ++r) {
        int orow = orow0 + r;
        if (orow < M) {
          float v = (acc[rt][ct][r] + bb) * dv[r];
          outb[(size_t)orow * 128 + col] = f2bf(v);
        }
      }
    }
  }
}

// ---------------- fused layer: aggregate (gather) -> LDS tile -> conv GEMM + BN + ReLU ----------------
// block = 64 nodes, 8 waves (512 thr).
// Phase A: wave w aggregates rows w*8..w*8+7 (agg3 access pattern), packs bf16 pairs
//          into swizzled LDS tile: u32 col c stored at c ^ ((row&15)<<2).
// Phase B: wave w computes output subtile rows (w&3)*16, cols (w>>2)*64.
// MODE 1: v = dis[row]*relu(BN(acc+bias));  MODE 2: v = relu(BN(acc+bias))

template<int MODE>
__global__ __launch_bounds__(512) void fused_layer(
    const unsigned short* __restrict__ xsb,
    const int* __restrict__ row_ptr, const int* __restrict__ csr_col,
    const float* __restrict__ dis,
    const unsigned short* __restrict__ BThi, const unsigned short* __restrict__ BTlo,
    const float* __restrict__ bias,
    const float* __restrict__ g, const float* __restrict__ be,
    const float* __restrict__ mn, const float* __restrict__ vr,
    unsigned short* __restrict__ outb) {
  __shared__ unsigned ytile[64 * 64];   // 16 KB, swizzled

  const int tid  = threadIdx.x;
  const int w    = tid >> 6;
  const int lane = tid & 63;
  const int nb   = blockIdx.x * 64;
  const unsigned* xsw = (const unsigned*)xsb;

  // ---- phase A: aggregate ----
  for (int i = 0; i < 8; ++i) {
    const int rloc = w * 8 + i;
    const int n = nb + rloc;
    float a0 = 0.f, a1 = 0.f;
    if (n < NN) {
      unsigned ws = xsw[(size_t)n * 64 + lane];
      a0 = lo16f(ws); a1 = hi16f(ws);
      const int s = row_ptr[n], e = row_ptr[n + 1];
      int j = s;
      for (; j + 8 <= e; j += 8) {
        int cc[8]; unsigned ww[8];
#pragma unroll
        for (int q = 0; q < 8; ++q) cc[q] = csr_col[j + q];
#pragma unroll
        for (int q = 0; q < 8; ++q) ww[q] = xsw[(size_t)cc[q] * 64 + lane];
#pragma unroll
        for (int q = 0; q < 8; ++q) { a0 += lo16f(ww[q]); a1 += hi16f(ww[q]); }
      }
      if (j + 4 <= e) {
        int cc[4]; unsigned ww[4];
#pragma unroll
        for (int q = 0; q < 4; ++q) cc[q] = csr_col[j + q];
#pragma unroll
        for (int q = 0; q < 4; ++q) ww[q] = xsw[(size_t)cc[q] * 64 + lane];
#pragma unroll
        for (int q = 0; q < 4; ++q) { a0 += lo16f(ww[q]); a1 += hi16f(ww[q]); }
        j += 4;
      }
      for (; j < e; ++j) {
        unsigned w0 = xsw[(size_t)csr_col[j] * 64 + lane];
        a0 += lo16f(w0);
        a1 += hi16f(w0);
      }
      float dv = dis[n];
      a0 *= dv; a1 *= dv;
    }
    unsigned short h0 = f2bf(a0), h1 = f2bf(a1);
    ytile[rloc * 64 + (lane ^ ((rloc & 15) << 2))] = (unsigned)h0 | ((unsigned)h1 << 16);
  }
  __syncthreads();

  // ---- phase B: GEMM 64x128, K=128 ----
  const int l15  = lane & 15;
  const int k4   = lane >> 4;           // 0..3
  const int r    = (w & 3) * 16 + l15;  // A-frag local row
  const int colh = (w >> 2) * 64;
  const int rsw  = (r & 15) << 2;

  f32x4 acc[4];
#pragma unroll
  for (int ct = 0; ct < 4; ++ct) acc[ct] = (f32x4){0.f, 0.f, 0.f, 0.f};

#pragma unroll
  for (int kb = 0; kb < 4; ++kb) {
    int q = kb * 4 + k4;
    int chunk = q ^ (rsw >> 2);
    short8 afrag = *(const short8*)&ytile[r * 64 + chunk * 4];
#pragma unroll
    for (int ct = 0; ct < 4; ++ct) {
      size_t woff = (size_t)(colh + ct * 16 + l15) * 128 + kb * 32 + k4 * 8;
      short8 bhi = *(const short8*)(BThi + woff);
      short8 blo = *(const short8*)(BTlo + woff);
      acc[ct] = __builtin_amdgcn_mfma_f32_16x16x32_bf16(afrag, bhi, acc[ct], 0, 0, 0);
      acc[ct] = __builtin_amdgcn_mfma_f32_16x16x32_bf16(afrag, blo, acc[ct], 0, 0, 0);
    }
  }

  // ---- epilogue ----
  const int orow0 = nb + (w & 3) * 16 + k4 * 4;
#pragma unroll
  for (int ct = 0; ct < 4; ++ct) {
    int col = colh + ct * 16 + l15;
    float bb = bias[col];
    float inv = rsqrtf(vr[col] + 1e-5f);
    float scale = g[col] * inv;
    float shift = be[col] - mn[col] * scale;
#pragma unroll
    for (int rr = 0; rr < 4; ++rr) {
      int orow = orow0 + rr;
      if (orow < NN) {
        float v = fmaxf((acc[ct][rr] + bb) * scale + shift, 0.f);
        if constexpr (MODE == 1) v *= dis[orow];
        outb[(size_t)orow * 128 + col] = f2bf(v);
      }
    }
  }
}

// ---------------- MFMA pair MLP (round-4/6 interleaved structure) ----------------

__global__ __launch_bounds__(256, 3) void mlp2_kernel(
    const unsigned short* __restrict__ xb, const int* __restrict__ pairs,
    const float* __restrict__ pf,
    const unsigned short* __restrict__ W1T, const float* __restrict__ b1,
    const unsigned short* __restrict__ W2T, const float* __restrict__ b2,
    const float* __restrict__ W3, const float* __restrict__ b3,
    float* __restrict__ out) {
  __shared__ unsigned short H1[128 * 136];

  const int tid  = threadIdx.x;
  const int lane = tid & 63;
  const int w    = tid >> 6;
  const int pb   = blockIdx.x * 128;
  const int rowbase = w * 32;
  const int l15  = lane & 15;
  const int khi  = (lane >> 4) * 8;
  const int rq   = (lane >> 4) * 4;

  int gp0 = pb + rowbase + l15;       if (gp0 >= NP) gp0 = NP - 1;
  int gp1 = pb + rowbase + 16 + l15;  if (gp1 >= NP) gp1 = NP - 1;
  const int2 pr0 = ((const int2*)pairs)[gp0];
  const int2 pr1 = ((const int2*)pairs)[gp1];

  short8 af[18];
#pragma unroll
  for (int kb = 0; kb < 4; ++kb) {
    af[kb]     = *(const short8*)(xb + (size_t)pr0.x * 128 + kb * 32 + khi);
    af[4 + kb] = *(const short8*)(xb + (size_t)pr0.y * 128 + kb * 32 + khi);
    af[9 + kb]     = *(const short8*)(xb + (size_t)pr1.x * 128 + kb * 32 + khi);
    af[9 + 4 + kb] = *(const short8*)(xb + (size_t)pr1.y * 128 + kb * 32 + khi);
  }
  {
    const float* q0 = pf + (size_t)gp0 * 32 + khi;
    const float* q1 = pf + (size_t)gp1 * 32 + khi;
    float4 u0 = *(const float4*)(q0), u1 = *(const float4*)(q0 + 4);
    float4 v0 = *(const float4*)(q1), v1 = *(const float4*)(q1 + 4);
    float fu[8] = {u0.x, u0.y, u0.z, u0.w, u1.x, u1.y, u1.z, u1.w};
    float fv[8] = {v0.x, v0.y, v0.z, v0.w, v1.x, v1.y, v1.z, v1.w};
#pragma unroll
    for (int j = 0; j < 8; ++j) {
      af[8][j]  = (short)f2bf(fu[j]);
      af[17][j] = (short)f2bf(fv[j]);
    }
  }

  f32x4 acc[2][8];
#pragma unroll
  for (int p = 0; p < 2; ++p)
#pragma unroll
    for (int c = 0; c < 8; ++c) acc[p][c] = (f32x4){0.f, 0.f, 0.f, 0.f};

#pragma unroll
  for (int kb = 0; kb < 9; ++kb) {
    const unsigned short* wrow = W1T + (size_t)kb * 32 + khi;
#pragma unroll
    for (int ct = 0; ct < 8; ++ct) {
      short8 bfrag = *(const short8*)(wrow + (size_t)(ct * 16 + l15) * 288);
      acc[0][ct] = __builtin_amdgcn_mfma_f32_16x16x32_bf16(af[kb], bfrag, acc[0][ct], 0, 0, 0);
      acc[1][ct] = __builtin_amdgcn_mfma_f32_16x16x32_bf16(af[9 + kb], bfrag, acc[1][ct], 0, 0, 0);
    }
  }

#pragma unroll
  for (int ct = 0; ct < 8; ++ct) {
    float bv = b1[ct * 16 + l15];
    int col = ct * 16 + l15;
#pragma unroll
    for (int p = 0; p < 2; ++p) {
#pragma unroll
      for (int r = 0; r < 4; ++r) {
        int row = rowbase + p * 16 + rq + r;
        float v = fmaxf(acc[p][ct][r] + bv, 0.f);
        H1[row * 136 + col] = f2bf(v);
      }
    }
  }
  __syncthreads();

  f32x4 acc2[2][4];
#pragma unroll
  for (int p = 0; p < 2; ++p)
#pragma unroll
    for (int c = 0; c < 4; ++c) acc2[p][c] = (f32x4){0.f, 0.f, 0.f, 0.f};

#pragma unroll
  for (int kb = 0; kb < 4; ++kb) {
    int ko = kb * 32 + khi;
    short8 a0 = *(const short8*)&H1[(rowbase + l15) * 136 + ko];
    short8 a1 = *(const short8*)&H1[(rowbase + 16 + l15) * 136 + ko];
    const unsigned short* wrow = W2T + (size_t)ko;
#pragma unroll
    for (int ct = 0; ct < 4; ++ct) {
      short8 bfrag = *(const short8*)(wrow + (size_t)(ct * 16 + l15) * 128);
      acc2[0][ct] = __builtin_amdgcn_mfma_f32_16x16x32_bf16(a0, bfrag, acc2[0][ct], 0, 0, 0);
      acc2[1][ct] = __builtin_amdgcn_mfma_f32_16x16x32_bf16(a1, bfrag, acc2[1][ct], 0, 0, 0);
    }
  }

  float w3v[4], b2v[4];
#pragma unroll
  for (int ct = 0; ct < 4; ++ct) {
    w3v[ct] = W3[ct * 16 + l15];
    b2v[ct] = b2[ct * 16 + l15];
  }
  float b3v = b3[0];
#pragma unroll
  for (int p = 0; p < 2; ++p) {
#pragma unroll
    for (int r = 0; r < 4; ++r) {
      float s = 0.f;
#pragma unroll
      for (int ct = 0; ct < 4; ++ct) {
        float h2 = fmaxf(acc2[p][ct][r] + b2v[ct], 0.f);
        s += h2 * w3v[ct];
      }
      s += __shfl_xor(s, 1);
      s += __shfl_xor(s, 2);
      s += __shfl_xor(s, 4);
      s += __shfl_xor(s, 8);
      int row = pb + rowbase + p * 16 + rq + r;
      if (l15 == 0 && row < NP) out[row] = s + b3v;
    }
  }
}

// ---------------- launch ----------------

extern "C" void kernel_launch(void* const* d_in, const int* in_sizes, int n_in,
                              void* d_out, int out_size, void* d_ws, size_t ws_size,
                              hipStream_t stream) {
  (void)in_sizes; (void)n_in; (void)out_size; (void)ws_size;
  const float* atom  = (const float*)d_in[0];
  const int*   eidx  = (const int*)d_in[1];
  const int*   pairs = (const int*)d_in[2];
  const float* pfeat = (const float*)d_in[3];
  const float* embW  = (const float*)d_in[4];
  const float* embB  = (const float*)d_in[5];
  const float* convW = (const float*)d_in[6];
  const float* convB = (const float*)d_in[7];
  const float* bng   = (const float*)d_in[8];
  const float* bnb   = (const float*)d_in[9];
  const float* bnm   = (const float*)d_in[10];
  const float* bnv   = (const float*)d_in[11];
  const float* W1    = (const float*)d_in[12];
  const float* b1    = (const float*)d_in[13];
  const float* W2    = (const float*)d_in[14];
  const float* b2    = (const float*)d_in[15];
  const float* W3    = (const float*)d_in[16];
  const float* b3    = (const float*)d_in[17];
  float* out = (float*)d_out;

  uintptr_t base = (uintptr_t)d_ws;
  auto alloc = [&](size_t bytes) -> uintptr_t {
    uintptr_t p = base;
    base += (bytes + 255) & ~(size_t)255;
    return p;
  };
  int*   counts  = (int*)alloc((size_t)NN * 4);
  int*   row_ptr = (int*)alloc((size_t)(NN + 1) * 4);
  int*   cursor  = (int*)alloc((size_t)NN * 4);
  int*   csr_col = (int*)alloc((size_t)NE * 4);
  float* dis     = (float*)alloc((size_t)NN * 4);
  int*   bsum    = (int*)alloc(64 * 4);
  int*   bbase   = (int*)alloc(64 * 4);
  unsigned short* xsA = (unsigned short*)alloc((size_t)NN * 128 * 2);
  unsigned short* xsB = (unsigned short*)alloc((size_t)NN * 128 * 2);
  unsigned short* embT_hi  = (unsigned short*)alloc(8192 * 2);
  unsigned short* embT_lo  = (unsigned short*)alloc(8192 * 2);
  unsigned short* convT_hi = (unsigned short*)alloc(49152 * 2);
  unsigned short* convT_lo = (unsigned short*)alloc(49152 * 2);
  unsigned short* W1T      = (unsigned short*)alloc(36864 * 2);
  unsigned short* W2T      = (unsigned short*)alloc(8192 * 2);

  const int* erow = eidx;
  const int* ecol = eidx + NE;

  hipMemsetAsync(counts, 0, (size_t)NN * 4, stream);
  count_kernel<<<(NE + 255) / 256, 256, 0, stream>>>(erow, counts);
  dis_kernel<<<(NN + 255) / 256, 256, 0, stream>>>(counts, dis);
  scan_partial<<<NB_SCAN, 256, 0, stream>>>(counts, bsum);
  scan_mid<<<1, 64, 0, stream>>>(bsum, bbase);
  scan_final<<<NB_SCAN, 256, 0, stream>>>(counts, bbase, row_ptr, cursor);
  fill_kernel<<<(NE + 255) / 256, 256, 0, stream>>>(erow, ecol, cursor, csr_col);
  prep_w<<<(102400 + 255) / 256, 256, 0, stream>>>(embW, convW, W1, W2,
                                                   embT_hi, embT_lo, convT_hi, convT_lo,
                                                   W1T, W2T);

  // xs0 = bf16( dis * (atom @ embW + embB) )
  embed_gemm<<<(NN + 127) / 128, 256, 0, stream>>>(
      atom, embT_hi, embT_lo, embB, dis, xsA, NN);

  const int NBLK = (NN + 63) / 64;
  // layer 0: A -> B
  fused_layer<1><<<NBLK, 512, 0, stream>>>(
      xsA, row_ptr, csr_col, dis,
      convT_hi + 0 * 16384, convT_lo + 0 * 16384, convB + 0 * 128,
      bng + 0 * 128, bnb + 0 * 128, bnm + 0 * 128, bnv + 0 * 128, xsB);
  // layer 1: B -> A
  fused_layer<1><<<NBLK, 512, 0, stream>>>(
      xsB, row_ptr, csr_col, dis,
      convT_hi + 1 * 16384, convT_lo + 1 * 16384, convB + 1 * 128,
      bng + 1 * 128, bnb + 1 * 128, bnm + 1 * 128, bnv + 1 * 128, xsA);
  // layer 2: A -> B (no dis prescale; feeds pair MLP)
  fused_layer<2><<<NBLK, 512, 0, stream>>>(
      xsA, row_ptr, csr_col, dis,
      convT_hi + 2 * 16384, convT_lo + 2 * 16384, convB + 2 * 128,
      bng + 2 * 128, bnb + 2 * 128, bnm + 2 * 128, bnv + 2 * 128, xsB);

  mlp2_kernel<<<(NP + 127) / 128, 256, 0, stream>>>(xsB, pairs, pfeat,
                                                    W1T, b1, W2T, b2, W3, b3, out);
}